// Round 7
// baseline (778.460 us; speedup 1.0000x reference)
//
#include <hip/hip_runtime.h>
#include <hip/hip_cooperative_groups.h>

namespace cg = cooperative_groups;

typedef __attribute__((ext_vector_type(8))) short bf16x8;
typedef __attribute__((ext_vector_type(4))) float f32x4;
typedef __attribute__((ext_vector_type(2))) float f32x2;

// bf16 round-to-nearest-even
__device__ inline unsigned short bf16_rtn(float f) {
  unsigned u = __float_as_uint(f);
  unsigned r = u + 0x7fffu + ((u >> 16) & 1u);
  return (unsigned short)(r >> 16);
}

// split fp32 into hi/lo bf16 (for W only)
__device__ inline void split_bf16(float f, unsigned short& hi, unsigned short& lo) {
  hi = bf16_rtn(f);
  float fh = __uint_as_float((unsigned)hi << 16);
  lo = bf16_rtn(f - fh);
}

// fp8 e4m3 (OCP) pack/unpack via HW converters
__device__ inline unsigned char f_to_fp8(float f) {
  int r = __builtin_amdgcn_cvt_pk_fp8_f32(f, f, 0, false);
  return (unsigned char)(r & 0xff);
}

// ---------------- cooperative CSR construction (replaces 6 dispatches) ----------------
// Phases: init | hist | scan1 | scan2 | scan3 | scatter, separated by grid.sync().
// All per-kernel math identical to the round-1 split kernels (same order -> same bits).
__global__ __launch_bounds__(256, 4)
void k_csr(const int* __restrict__ x, const int* __restrict__ ei,
           const int* __restrict__ batch,
           const float* __restrict__ Ws, const float* __restrict__ embed,
           int* __restrict__ deg, int* __restrict__ gpz,
           int N, int M, int E,
           unsigned short* __restrict__ wphi, unsigned short* __restrict__ wplo,
           float* __restrict__ T,
           unsigned char* __restrict__ t_a, unsigned char* __restrict__ t_b,
           float* __restrict__ dpk, int* __restrict__ rowptr,
           int* __restrict__ bsum, int* __restrict__ boff,
           int* __restrict__ gstart, int* __restrict__ gend,
           int* __restrict__ posr, int2* __restrict__ epack) {
  cg::grid_group grid = cg::this_grid();
  __shared__ int sdata[256];
  __shared__ int s2[512];

  const int tid = blockIdx.x * 256 + threadIdx.x;
  const int nth = gridDim.x * 256;
  const int* src = ei;
  const int* dst = ei + E;
  const int nbN = (N + 255) >> 8;

  // ---- phase A: init ----
  for (int i = tid; i < N; i += nth) deg[i] = 0;
  for (int i = tid; i < M; i += nth) gpz[i] = 0;
  for (int idx = tid; idx < 3 * 16384; idx += nth) {
    int l = idx >> 14;
    int rr = idx & 16383;
    const float* W = Ws + (size_t)(l + 1) * 16384;
    int j = rr & 7;
    int lane = (rr >> 3) & 63;
    int c = (rr >> 9) & 3;
    int ct = rr >> 11;
    int k = c * 32 + ((lane >> 4) * 8) + j;
    int n = ct * 16 + (lane & 15);
    unsigned short hi, lo;
    split_bf16(W[k * 128 + n], hi, lo);
    wphi[(size_t)l * 16384 + rr] = hi;
    wplo[(size_t)l * 16384 + rr] = lo;
  }
  for (int idx = tid; idx < 256; idx += nth) {
    int r = idx >> 7, c = idx & 127;
    float acc = 0.f;
    for (int k = 0; k < 128; ++k)
      acc += embed[r * 128 + k] * Ws[k * 128 + c];
    T[r * 128 + c] = acc;
  }
  for (int idx = tid; idx < 64; idx += nth) {
    if (idx < 32) ((unsigned*)(t_a + (size_t)N * 128))[idx] = 0u;
    else          ((unsigned*)(t_b + (size_t)N * 128))[idx - 32] = 0u;
  }
  grid.sync();

  // ---- phase B: hist ----
  for (int e = tid; e < E; e += nth) posr[e] = atomicAdd(&deg[dst[e]], 1);
  grid.sync();

  // ---- phase C: scan1 (per-256-segment scan) + dpk + group bounds ----
  for (int s = blockIdx.x; s < nbN; s += gridDim.x) {
    int t = threadIdx.x;
    int i = s * 256 + t;
    int v = (i < N) ? deg[i] : 0;
    if (i < N) {
      float di = rsqrtf((float)v + 1.0f);
      dpk[i] = x[i] ? -di : di;
      int g = batch[i];
      if (i == 0 || batch[i - 1] != g) gstart[g] = i;
      if (i == N - 1 || batch[i + 1] != g) gend[g] = i + 1;
    }
    sdata[t] = v;
    __syncthreads();
    for (int off = 1; off < 256; off <<= 1) {
      int u = (t >= off) ? sdata[t - off] : 0;
      __syncthreads();
      sdata[t] += u;
      __syncthreads();
    }
    if (i < N) rowptr[i] = sdata[t] - v;
    if (t == 255) bsum[s] = sdata[255];
    __syncthreads();
  }
  grid.sync();

  // ---- phase D: scan2 (block 0 scans the <=512 block sums) ----
  if (blockIdx.x == 0) {
    int t = threadIdx.x;
    int v0 = (t < nbN) ? bsum[t] : 0;
    int v1 = (t + 256 < nbN) ? bsum[t + 256] : 0;
    s2[t] = v0;
    s2[t + 256] = v1;
    __syncthreads();
    for (int off = 1; off < 512; off <<= 1) {
      int u0 = (t >= off) ? s2[t - off] : 0;
      int u1 = (t + 256 >= off) ? s2[t + 256 - off] : 0;
      __syncthreads();
      s2[t] += u0;
      s2[t + 256] += u1;
      __syncthreads();
    }
    boff[t] = s2[t] - v0;
    boff[t + 256] = s2[t + 256] - v1;
  }
  grid.sync();

  // ---- phase E: scan3 ----
  for (int i = tid; i < N; i += nth) rowptr[i] += boff[i >> 8];
  if (tid == 0) rowptr[N] = E;
  grid.sync();

  // ---- phase F: scatter ----
  for (int e = tid; e < E; e += nth) {
    int s = src[e], d = dst[e];
    int pos = rowptr[d] + posr[e];
    epack[pos] = make_int2(s, __float_as_int(dpk[s]));
  }
}

// ---------------- 8-lane-group gather (round-1 form — measured optimum) ----------------
// 8 nodes per wave, 8 lanes per node, 16 B (dwordx4) per lane -> one load
// instruction fetches a full 128 B t' row for 8 nodes at once.
// 16 straight-line unguarded loads per node (out-of-degree slots padded with
// the all-zero row at index N) -> no per-load predication (r14 lesson).
// LEARNED (r0-r5): gather cost ~43-50us is invariant to wave concurrency
// (88->256 rows in flight), to L2 hit rate (slice-major XCD pinning), and to
// HBM traffic — it is at its structural floor. Do not restructure.

__device__ inline void acc16(float* a, uint4 p) {
  f32x2 v;
  v = __builtin_amdgcn_cvt_pk_f32_fp8((int)p.x, false); a[0]  += v.x; a[1]  += v.y;
  v = __builtin_amdgcn_cvt_pk_f32_fp8((int)p.x, true);  a[2]  += v.x; a[3]  += v.y;
  v = __builtin_amdgcn_cvt_pk_f32_fp8((int)p.y, false); a[4]  += v.x; a[5]  += v.y;
  v = __builtin_amdgcn_cvt_pk_f32_fp8((int)p.y, true);  a[6]  += v.x; a[7]  += v.y;
  v = __builtin_amdgcn_cvt_pk_f32_fp8((int)p.z, false); a[8]  += v.x; a[9]  += v.y;
  v = __builtin_amdgcn_cvt_pk_f32_fp8((int)p.z, true);  a[10] += v.x; a[11] += v.y;
  v = __builtin_amdgcn_cvt_pk_f32_fp8((int)p.w, false); a[12] += v.x; a[13] += v.y;
  v = __builtin_amdgcn_cvt_pk_f32_fp8((int)p.w, true);  a[14] += v.x; a[15] += v.y;
}

__device__ inline void gather8(const unsigned char* __restrict__ tin,
                               const int2* __restrict__ epack,
                               int r0, int deg, int l8, int N,
                               float* a) {
  int dcap = deg < 16 ? deg : 16;
  int slo = N, shi = N;
  if (2 * l8 < dcap)     slo = epack[r0 + 2 * l8].x;
  if (2 * l8 + 1 < dcap) shi = epack[r0 + 2 * l8 + 1].x;

  uint4 p[16];
  #pragma unroll
  for (int k = 0; k < 8; ++k) {
    int se = __shfl(slo, k, 8);
    int so = __shfl(shi, k, 8);
    p[2 * k]     = *(const uint4*)(tin + (size_t)((unsigned)se * 128u + ((unsigned)l8 << 4)));
    p[2 * k + 1] = *(const uint4*)(tin + (size_t)((unsigned)so * 128u + ((unsigned)l8 << 4)));
  }
  #pragma unroll
  for (int k = 0; k < 16; ++k) acc16(a, p[k]);

  if (__builtin_expect(deg > 16, 0)) {
    for (int e = r0 + 16; e < r0 + deg; ++e) {
      int s = epack[e].x;
      uint4 q = *(const uint4*)(tin + (size_t)((unsigned)s * 128u + ((unsigned)l8 << 4)));
      acc16(a, q);
    }
  }
}

// ---------------- standalone aggregate: h = relu(dinv_i*(sum t' + t'_i) + b) ----------------
__global__ __launch_bounds__(256)
void k_agg(const unsigned char* __restrict__ tin,
           const int* __restrict__ rowptr,
           const int2* __restrict__ epack,
           const float* __restrict__ dpk, const float* __restrict__ bvec,
           unsigned short* __restrict__ h, int N) {
  int lane = threadIdx.x & 63;
  int g8 = lane >> 3, l8 = lane & 7;
  int wid = (blockIdx.x * 256 + threadIdx.x) >> 6;
  int i = wid * 8 + g8;
  if (i >= N) return;
  int r0 = rowptr[i], r1 = rowptr[i + 1];
  uint4 ps = *(const uint4*)(tin + (size_t)i * 128 + (l8 << 4));
  float dp = dpk[i];

  float a[16];
  #pragma unroll
  for (int k = 0; k < 16; ++k) a[k] = 0.f;
  gather8(tin, epack, r0, r1 - r0, l8, N, a);
  acc16(a, ps);

  float di = fabsf(dp);
  const float4* bp = (const float4*)(bvec + 16 * l8);
  float4 b0 = bp[0], b1 = bp[1], b2 = bp[2], b3 = bp[3];
  float bb[16] = {b0.x, b0.y, b0.z, b0.w, b1.x, b1.y, b1.z, b1.w,
                  b2.x, b2.y, b2.z, b2.w, b3.x, b3.y, b3.z, b3.w};
  unsigned u[8];
  #pragma unroll
  for (int k = 0; k < 8; ++k) {
    float v0 = fmaxf(di * a[2 * k]     + bb[2 * k],     0.f);
    float v1 = fmaxf(di * a[2 * k + 1] + bb[2 * k + 1], 0.f);
    u[k] = (unsigned)bf16_rtn(v0) | ((unsigned)bf16_rtn(v1) << 16);
  }
  uint4* hp = (uint4*)(h + (size_t)i * 128 + 16 * l8);
  hp[0] = make_uint4(u[0], u[1], u[2], u[3]);
  hp[1] = make_uint4(u[4], u[5], u[6], u[7]);
}

// ---------------- fused final aggregate + mean-pool (block = 32 nodes) ----------------
__global__ __launch_bounds__(256)
void k_agg_pool(const unsigned char* __restrict__ tin,
                const int* __restrict__ rowptr,
                const int2* __restrict__ epack,
                const float* __restrict__ dpk, const float* __restrict__ bvec,
                const int* __restrict__ batch,
                float* __restrict__ pooled, int N) {
  __shared__ float sh[32][128];
  __shared__ int sg[32];
  int lane = threadIdx.x & 63;
  int g8 = lane >> 3, l8 = lane & 7;
  int nloc = (threadIdx.x >> 6) * 8 + g8;
  int i = blockIdx.x * 32 + nloc;
  if (threadIdx.x < 32) sg[threadIdx.x] = -1;
  __syncthreads();
  if (i < N) {
    int r0 = rowptr[i], r1 = rowptr[i + 1];
    uint4 ps = *(const uint4*)(tin + (size_t)i * 128 + (l8 << 4));
    float dp = dpk[i];

    float a[16];
    #pragma unroll
    for (int k = 0; k < 16; ++k) a[k] = 0.f;
    gather8(tin, epack, r0, r1 - r0, l8, N, a);
    acc16(a, ps);

    float di = fabsf(dp);
    const float4* bp = (const float4*)(bvec + 16 * l8);
    float4 b0 = bp[0], b1 = bp[1], b2 = bp[2], b3 = bp[3];
    float bb[16] = {b0.x, b0.y, b0.z, b0.w, b1.x, b1.y, b1.z, b1.w,
                    b2.x, b2.y, b2.z, b2.w, b3.x, b3.y, b3.z, b3.w};
    #pragma unroll
    for (int k = 0; k < 16; ++k)
      sh[nloc][16 * l8 + k] = di * a[k] + bb[k];
    if (l8 == 0) sg[nloc] = batch[i];
  }
  __syncthreads();
  if (threadIdx.x < 128) {
    int c = threadIdx.x;
    float acc = 0.f;
    int cur = sg[0];
    #pragma unroll
    for (int w2 = 0; w2 < 32; ++w2) {
      int gw = sg[w2];
      if (gw < 0) break;
      if (gw != cur) {
        atomicAdd(&pooled[cur * 128 + c], acc);
        acc = 0.f;
        cur = gw;
      }
      acc += sh[w2][c];
    }
    atomicAdd(&pooled[cur * 128 + c], acc);
  }
}

// ---------------- standalone MFMA GEMM: t' = dinv * (h @ W), fp8 out (round-1 form) ----
__global__ void k_gemm(const unsigned short* __restrict__ h,
                       const unsigned short* __restrict__ wphi,
                       const unsigned short* __restrict__ wplo,
                       const float* __restrict__ dpk,
                       unsigned char* __restrict__ tout, int N) {
  int wave = threadIdx.x >> 6;
  int lane = threadIdx.x & 63;
  int r0 = (blockIdx.x * 4 + wave) * 32;
  if (r0 >= N) return;
  int q = lane >> 4;
  int m = lane & 15;
  const bf16x8* bh_base = (const bf16x8*)wphi;
  const bf16x8* bl_base = (const bf16x8*)wplo;

  f32x4 acc[2][8];
  #pragma unroll
  for (int tt = 0; tt < 2; ++tt)
    #pragma unroll
    for (int ct = 0; ct < 8; ++ct)
      acc[tt][ct] = (f32x4){0.f, 0.f, 0.f, 0.f};

  for (int c = 0; c < 4; ++c) {
    bf16x8 a0 = *(const bf16x8*)(h + (size_t)(r0 + m) * 128 + c * 32 + q * 8);
    bf16x8 a1 = *(const bf16x8*)(h + (size_t)(r0 + 16 + m) * 128 + c * 32 + q * 8);
    #pragma unroll
    for (int ct = 0; ct < 8; ++ct) {
      bf16x8 bh = bh_base[(ct * 4 + c) * 64 + lane];
      bf16x8 bl = bl_base[(ct * 4 + c) * 64 + lane];
      acc[0][ct] = __builtin_amdgcn_mfma_f32_16x16x32_bf16(a0, bh, acc[0][ct], 0, 0, 0);
      acc[0][ct] = __builtin_amdgcn_mfma_f32_16x16x32_bf16(a0, bl, acc[0][ct], 0, 0, 0);
      acc[1][ct] = __builtin_amdgcn_mfma_f32_16x16x32_bf16(a1, bh, acc[1][ct], 0, 0, 0);
      acc[1][ct] = __builtin_amdgcn_mfma_f32_16x16x32_bf16(a1, bl, acc[1][ct], 0, 0, 0);
    }
  }

  #pragma unroll
  for (int tt = 0; tt < 2; ++tt)
    #pragma unroll
    for (int ct = 0; ct < 8; ++ct)
      #pragma unroll
      for (int r = 0; r < 4; ++r) {
        int row = r0 + tt * 16 + q * 4 + r;
        if (row < N) {
          float sc = fabsf(dpk[row]);
          tout[(size_t)row * 128 + ct * 16 + m] = f_to_fp8(sc * acc[tt][ct][r]);
        }
      }
}

// ---------------- fused layer0 (rank-2) + gemm1 -> t1' (round-1 form) ----------------
__device__ inline void gemm_tile8(const unsigned short* hT,
                                  const unsigned short* __restrict__ wphi,
                                  const unsigned short* __restrict__ wplo,
                                  const float* __restrict__ dpk,
                                  unsigned char* __restrict__ tout, int i0, int N) {
  int ct = threadIdx.x >> 6;
  int lane = threadIdx.x & 63;
  int q = lane >> 4;
  int m = lane & 15;
  const bf16x8* bh_base = (const bf16x8*)wphi;
  const bf16x8* bl_base = (const bf16x8*)wplo;

  f32x4 acc0 = (f32x4){0.f, 0.f, 0.f, 0.f};
  f32x4 acc1 = (f32x4){0.f, 0.f, 0.f, 0.f};

  #pragma unroll
  for (int c = 0; c < 4; ++c) {
    bf16x8 a0 = *(const bf16x8*)(hT + (m) * 136 + c * 32 + q * 8);
    bf16x8 a1 = *(const bf16x8*)(hT + (16 + m) * 136 + c * 32 + q * 8);
    bf16x8 bh = bh_base[(ct * 4 + c) * 64 + lane];
    bf16x8 bl = bl_base[(ct * 4 + c) * 64 + lane];
    acc0 = __builtin_amdgcn_mfma_f32_16x16x32_bf16(a0, bh, acc0, 0, 0, 0);
    acc0 = __builtin_amdgcn_mfma_f32_16x16x32_bf16(a0, bl, acc0, 0, 0, 0);
    acc1 = __builtin_amdgcn_mfma_f32_16x16x32_bf16(a1, bh, acc1, 0, 0, 0);
    acc1 = __builtin_amdgcn_mfma_f32_16x16x32_bf16(a1, bl, acc1, 0, 0, 0);
  }

  #pragma unroll
  for (int r = 0; r < 4; ++r) {
    int row0 = i0 + q * 4 + r;
    int row1 = row0 + 16;
    if (row0 < N) {
      float sc = fabsf(dpk[row0]);
      tout[(size_t)row0 * 128 + ct * 16 + m] = f_to_fp8(sc * acc0[r]);
    }
    if (row1 < N) {
      float sc = fabsf(dpk[row1]);
      tout[(size_t)row1 * 128 + ct * 16 + m] = f_to_fp8(sc * acc1[r]);
    }
  }
}

__global__ __launch_bounds__(512)
void k_l1_gemm(const int* __restrict__ rowptr,
               const int2* __restrict__ epack,
               const float* __restrict__ dpk, const float* __restrict__ T,
               const float* __restrict__ b0,
               const unsigned short* __restrict__ wphi,
               const unsigned short* __restrict__ wplo,
               unsigned char* __restrict__ tout, int N) {
  __shared__ unsigned short hT[32 * 136];
  int wave = threadIdx.x >> 6;
  int lane = threadIdx.x & 63;
  int i0 = blockIdx.x * 32;

  for (int j = wave * 4; j < wave * 4 + 4; ++j) {
    int i = i0 + j;
    if (i >= N) break;
    int r0 = rowptr[i], r1 = rowptr[i + 1];
    float sabs = 0.f, sneg = 0.f;
    for (int e = r0 + lane; e < r1; e += 64) {
      float wv = __int_as_float(epack[e].y);   // dpk[src]
      float aw = fabsf(wv);
      sabs += aw;
      if (wv < 0.f) sneg += aw;
    }
    for (int mm = 32; mm >= 1; mm >>= 1) {
      sabs += __shfl_xor(sabs, mm, 64);
      sneg += __shfl_xor(sneg, mm, 64);
    }
    float dp = dpk[i];
    float di = fabsf(dp);
    float sn = di * di;
    float c1 = di * sneg;
    float c0 = di * (sabs - sneg);
    if (dp < 0.f) c1 += sn; else c0 += sn;
    float v0 = fmaxf(c0 * T[2 * lane]     + c1 * T[128 + 2 * lane]     + b0[2 * lane],     0.f);
    float v1 = fmaxf(c0 * T[2 * lane + 1] + c1 * T[128 + 2 * lane + 1] + b0[2 * lane + 1], 0.f);
    *(unsigned*)&hT[j * 136 + 2 * lane] = (unsigned)bf16_rtn(v0) | ((unsigned)bf16_rtn(v1) << 16);
  }
  __syncthreads();
  gemm_tile8(hT, wphi, wplo, dpk, tout, i0, N);
}

// ---------------- output head ----------------
__global__ void k_out(const float* __restrict__ pooled, const int* __restrict__ gstart,
                      const int* __restrict__ gend, const float* __restrict__ W_out,
                      const float* __restrict__ b_out, float* __restrict__ out, int G) {
  __shared__ float sp[128];
  int g = blockIdx.x;
  int j = threadIdx.x;
  float cnt = (float)(gend[g] - gstart[g]);
  sp[j] = pooled[g * 128 + j] / fmaxf(cnt, 1.f);
  __syncthreads();
  if (j < 2) {
    float o = b_out[j];
    for (int k = 0; k < 128; ++k)
      o += sp[k] * W_out[k * 2 + j];
    out[g * 2 + j] = o;
  }
}

extern "C" void kernel_launch(void* const* d_in, const int* in_sizes, int n_in,
                              void* d_out, int out_size, void* d_ws, size_t ws_size,
                              hipStream_t stream) {
  const int*   x     = (const int*)d_in[0];
  const int*   ei    = (const int*)d_in[1];
  const int*   batch = (const int*)d_in[2];
  const float* embed = (const float*)d_in[3];
  const float* Ws    = (const float*)d_in[4];
  const float* bs    = (const float*)d_in[5];
  const float* W_out = (const float*)d_in[6];
  const float* b_out = (const float*)d_in[7];
  float* out = (float*)d_out;

  int N = in_sizes[2];
  int E = in_sizes[1] / 2;
  int G = out_size / 2;

  char* w = (char*)d_ws;
  auto alloc = [&](size_t bytes) {
    char* p = w;
    w += (bytes + 255) & ~(size_t)255;
    return p;
  };
  int*   deg    = (int*)  alloc((size_t)N * 4);
  float* dpk    = (float*)alloc((size_t)N * 4);
  int*   rowptr = (int*)  alloc((size_t)(N + 1) * 4);
  int*   posr   = (int*)  alloc((size_t)E * 4);
  int*   bsum   = (int*)  alloc(512 * 4);
  int*   boff   = (int*)  alloc(512 * 4);
  // gstart/gend/pooled contiguous -> zeroed together in k_csr phase A
  int*   gstart = (int*)  alloc((size_t)G * 4);
  int*   gend   = (int*)  alloc((size_t)G * 4);
  float* pooled = (float*)alloc((size_t)G * 128 * 4);
  float* T      = (float*)alloc(256 * 4);
  unsigned short* wphi = (unsigned short*)alloc((size_t)3 * 16384 * 2);
  unsigned short* wplo = (unsigned short*)alloc((size_t)3 * 16384 * 2);
  int2*  epack  = (int2*) alloc((size_t)E * 8);
  unsigned short* h = (unsigned short*)alloc((size_t)N * 128 * 2);
  unsigned char* t_a = (unsigned char*)alloc((size_t)(N + 1) * 128);  // +1: zero row
  unsigned char* t_b = (unsigned char*)alloc((size_t)(N + 1) * 128);  // +1: zero row

  int ntile = (N + 31) / 32;
  int nagg = (N + 31) / 32;         // 32 nodes/block (8 per wave x 4 waves)
  int ngemm = (N + 127) / 128;      // 4 waves x 32 rows
  int M = G * 130;                  // gstart + gend + pooled (4B elems, contiguous)

  // ---- single cooperative dispatch for all CSR construction ----
  void* cargs[] = {
    (void*)&x, (void*)&ei, (void*)&batch, (void*)&Ws, (void*)&embed,
    (void*)&deg, (void*)&gstart, (void*)&N, (void*)&M, (void*)&E,
    (void*)&wphi, (void*)&wplo, (void*)&T, (void*)&t_a, (void*)&t_b,
    (void*)&dpk, (void*)&rowptr, (void*)&bsum, (void*)&boff,
    (void*)&gstart, (void*)&gend, (void*)&posr, (void*)&epack
  };
  hipLaunchCooperativeKernel((void*)k_csr, dim3(1024), dim3(256), cargs, 0, stream);

  // layer0 (rank-2) + gemm1 -> t_a (= dinv * h1@W1)
  k_l1_gemm<<<ntile, 512, 0, stream>>>(rowptr, epack, dpk, T, bs,
                                       wphi, wplo, t_a, N);
  // layer1: h = relu(dinv*(sum t_a' + self) + b1); t_b = dinv * h@W2
  k_agg<<<nagg, 256, 0, stream>>>(t_a, rowptr, epack, dpk, bs + 128, h, N);
  k_gemm<<<ngemm, 256, 0, stream>>>(h, wphi + 16384, wplo + 16384, dpk, t_b, N);
  // layer2
  k_agg<<<nagg, 256, 0, stream>>>(t_b, rowptr, epack, dpk, bs + 256, h, N);
  k_gemm<<<ngemm, 256, 0, stream>>>(h, wphi + 32768, wplo + 32768, dpk, t_a, N);
  // layer3 (no relu) fused with mean-pool
  k_agg_pool<<<nagg, 256, 0, stream>>>(t_a, rowptr, epack, dpk, bs + 384,
                                       batch, pooled, N);
  k_out<<<G, 128, 0, stream>>>(pooled, gstart, gend, W_out, b_out, out, G);
}

// Round 8
// 283.083 us; speedup vs baseline: 2.7499x; 2.7499x over previous
//
#include <hip/hip_runtime.h>

typedef __attribute__((ext_vector_type(8))) short bf16x8;
typedef __attribute__((ext_vector_type(4))) float f32x4;
typedef __attribute__((ext_vector_type(2))) float f32x2;

// bf16 round-to-nearest-even
__device__ inline unsigned short bf16_rtn(float f) {
  unsigned u = __float_as_uint(f);
  unsigned r = u + 0x7fffu + ((u >> 16) & 1u);
  return (unsigned short)(r >> 16);
}

// split fp32 into hi/lo bf16 (for W only)
__device__ inline void split_bf16(float f, unsigned short& hi, unsigned short& lo) {
  hi = bf16_rtn(f);
  float fh = __uint_as_float((unsigned)hi << 16);
  lo = bf16_rtn(f - fh);
}

// fp8 e4m3 (OCP) pack/unpack via HW converters
__device__ inline unsigned char f_to_fp8(float f) {
  int r = __builtin_amdgcn_cvt_pk_fp8_f32(f, f, 0, false);
  return (unsigned char)(r & 0xff);
}

// ---------------- init: zero deg + gstart/gend/pooled, prep W hi/lo, T, zero-row ----------------
__global__ void k_init(int* __restrict__ deg, int* __restrict__ gpz, int N, int M,
                       const float* __restrict__ Ws, const float* __restrict__ embed,
                       unsigned short* __restrict__ wphi,
                       unsigned short* __restrict__ wplo,
                       float* __restrict__ T,
                       unsigned char* __restrict__ t_a,
                       unsigned char* __restrict__ t_b) {
  int i = blockIdx.x * 256 + threadIdx.x;
  if (i < N) deg[i] = 0;
  if (i < M) gpz[i] = 0;
  int l = blockIdx.x;
  if (l < 3) {
    const float* W = Ws + (size_t)(l + 1) * 128 * 128;
    unsigned short* dh = wphi + (size_t)l * 16384;
    unsigned short* dl = wplo + (size_t)l * 16384;
    for (int idx = threadIdx.x; idx < 16384; idx += 256) {
      int j = idx & 7;
      int lane = (idx >> 3) & 63;
      int c = (idx >> 9) & 3;
      int ct = idx >> 11;
      int k = c * 32 + ((lane >> 4) * 8) + j;
      int n = ct * 16 + (lane & 15);
      unsigned short hi, lo;
      split_bf16(W[k * 128 + n], hi, lo);
      dh[idx] = hi;
      dl[idx] = lo;
    }
  } else if (l == 3) {
    int t = threadIdx.x;
    int r = t >> 7, c = t & 127;
    float acc = 0.f;
    for (int k = 0; k < 128; ++k)
      acc += embed[r * 128 + k] * Ws[k * 128 + c];
    T[r * 128 + c] = acc;
  } else if (l == 4) {
    // zero-row at index N for both t buffers (pad target for the gather).
    // GEMMs only ever write rows < N, so this persists across layers.
    int t = threadIdx.x;
    if (t < 32)      ((unsigned*)(t_a + (size_t)N * 128))[t] = 0u;
    else if (t < 64) ((unsigned*)(t_b + (size_t)N * 128))[t - 32] = 0u;
  }
}

// ---------------- CSR construction (round-1 scheme) ----------------

__global__ void k_hist(const int* __restrict__ dst, int* __restrict__ deg,
                       int* __restrict__ posr, int E) {
  int e = blockIdx.x * 256 + threadIdx.x;
  if (e < E) posr[e] = atomicAdd(&deg[dst[e]], 1);
}

__global__ void k_scan1(const int* __restrict__ deg, int* __restrict__ rowptr,
                        int* __restrict__ bsum, float* __restrict__ dpk,
                        const int* __restrict__ x, const int* __restrict__ batch,
                        int* __restrict__ gstart, int* __restrict__ gend, int N) {
  __shared__ int s[256];
  int t = threadIdx.x;
  int i = blockIdx.x * 256 + t;
  int v = (i < N) ? deg[i] : 0;
  if (i < N) {
    float di = rsqrtf((float)v + 1.0f);
    dpk[i] = x[i] ? -di : di;
    int g = batch[i];
    if (i == 0 || batch[i - 1] != g) gstart[g] = i;
    if (i == N - 1 || batch[i + 1] != g) gend[g] = i + 1;
  }
  s[t] = v;
  __syncthreads();
  for (int off = 1; off < 256; off <<= 1) {
    int u = (t >= off) ? s[t - off] : 0;
    __syncthreads();
    s[t] += u;
    __syncthreads();
  }
  if (i < N) rowptr[i] = s[t] - v;
  if (t == 255) bsum[blockIdx.x] = s[255];
}

// scan2+scan3 merged: each block redundantly reduces bsum[0..blockIdx) (~391 ints,
// pure reads, no atomics) then applies the offset. Saves one dispatch vs round-1.
__global__ void k_scanB(int* __restrict__ rowptr, const int* __restrict__ bsum,
                        int N, int E) {
  __shared__ int red[256];
  int b = blockIdx.x, t = threadIdx.x;
  int s = 0;
  for (int j = t; j < b; j += 256) s += bsum[j];
  red[t] = s;
  __syncthreads();
  for (int off = 128; off >= 1; off >>= 1) {
    if (t < off) red[t] += red[t + off];
    __syncthreads();
  }
  int boff = red[0];
  int i = b * 256 + t;
  if (i < N) rowptr[i] += boff;
  if (i == 0) rowptr[N] = E;
}

__global__ void k_scatter(const int* __restrict__ src, const int* __restrict__ dst,
                          const int* __restrict__ posr, const int* __restrict__ rowptr,
                          const float* __restrict__ dpk,
                          int2* __restrict__ epack, int E) {
  int e = blockIdx.x * 256 + threadIdx.x;
  if (e >= E) return;
  int s = src[e], d = dst[e];
  int pos = rowptr[d] + posr[e];
  epack[pos] = make_int2(s, __float_as_int(dpk[s]));
}

// ---------------- 8-lane-group gather (round-1 form — measured optimum) ----------------
// 8 nodes per wave, 8 lanes per node, 16 B (dwordx4) per lane -> one load
// instruction fetches a full 128 B t' row for 8 nodes at once.
// 16 straight-line unguarded loads per node (out-of-degree slots padded with
// the all-zero row at index N) -> no per-load predication (r14 lesson).
// LEARNED (r0-r7): gather cost ~43-50us is invariant to wave concurrency
// (88->256 rows in flight), to L2 hit rate (slice-major XCD pinning), and to
// HBM traffic — it is at its structural floor. Do not restructure.
// Also learned: cooperative grid.sync costs ~100us/barrier at 1024 blocks (r7);
// never use it to save launch gaps.

__device__ inline void acc16(float* a, uint4 p) {
  f32x2 v;
  v = __builtin_amdgcn_cvt_pk_f32_fp8((int)p.x, false); a[0]  += v.x; a[1]  += v.y;
  v = __builtin_amdgcn_cvt_pk_f32_fp8((int)p.x, true);  a[2]  += v.x; a[3]  += v.y;
  v = __builtin_amdgcn_cvt_pk_f32_fp8((int)p.y, false); a[4]  += v.x; a[5]  += v.y;
  v = __builtin_amdgcn_cvt_pk_f32_fp8((int)p.y, true);  a[6]  += v.x; a[7]  += v.y;
  v = __builtin_amdgcn_cvt_pk_f32_fp8((int)p.z, false); a[8]  += v.x; a[9]  += v.y;
  v = __builtin_amdgcn_cvt_pk_f32_fp8((int)p.z, true);  a[10] += v.x; a[11] += v.y;
  v = __builtin_amdgcn_cvt_pk_f32_fp8((int)p.w, false); a[12] += v.x; a[13] += v.y;
  v = __builtin_amdgcn_cvt_pk_f32_fp8((int)p.w, true);  a[14] += v.x; a[15] += v.y;
}

__device__ inline void gather8(const unsigned char* __restrict__ tin,
                               const int2* __restrict__ epack,
                               int r0, int deg, int l8, int N,
                               float* a) {
  int dcap = deg < 16 ? deg : 16;
  // register cache of up to 16 src indices; pad slots point at zero row N
  int slo = N, shi = N;
  if (2 * l8 < dcap)     slo = epack[r0 + 2 * l8].x;
  if (2 * l8 + 1 < dcap) shi = epack[r0 + 2 * l8 + 1].x;

  uint4 p[16];
  #pragma unroll
  for (int k = 0; k < 8; ++k) {
    int se = __shfl(slo, k, 8);       // edge 2k
    int so = __shfl(shi, k, 8);       // edge 2k+1
    p[2 * k]     = *(const uint4*)(tin + (size_t)((unsigned)se * 128u + ((unsigned)l8 << 4)));
    p[2 * k + 1] = *(const uint4*)(tin + (size_t)((unsigned)so * 128u + ((unsigned)l8 << 4)));
  }
  #pragma unroll
  for (int k = 0; k < 16; ++k) acc16(a, p[k]);

  if (__builtin_expect(deg > 16, 0)) {  // rare tail (P ~ 4e-4 at mean deg 6.4)
    for (int e = r0 + 16; e < r0 + deg; ++e) {
      int s = epack[e].x;
      uint4 q = *(const uint4*)(tin + (size_t)((unsigned)s * 128u + ((unsigned)l8 << 4)));
      acc16(a, q);
    }
  }
}

// ---------------- standalone aggregate: h = relu(dinv_i*(sum t' + t'_i) + b) ----------------
__global__ __launch_bounds__(256)
void k_agg(const unsigned char* __restrict__ tin,
           const int* __restrict__ rowptr,
           const int2* __restrict__ epack,
           const float* __restrict__ dpk, const float* __restrict__ bvec,
           unsigned short* __restrict__ h, int N) {
  int lane = threadIdx.x & 63;
  int g8 = lane >> 3, l8 = lane & 7;
  int wid = (blockIdx.x * 256 + threadIdx.x) >> 6;
  int i = wid * 8 + g8;
  if (i >= N) return;
  int r0 = rowptr[i], r1 = rowptr[i + 1];
  // prefetch independents before the gather
  uint4 ps = *(const uint4*)(tin + (size_t)i * 128 + (l8 << 4));
  float dp = dpk[i];

  float a[16];
  #pragma unroll
  for (int k = 0; k < 16; ++k) a[k] = 0.f;
  gather8(tin, epack, r0, r1 - r0, l8, N, a);
  acc16(a, ps);  // self term

  float di = fabsf(dp);
  const float4* bp = (const float4*)(bvec + 16 * l8);
  float4 b0 = bp[0], b1 = bp[1], b2 = bp[2], b3 = bp[3];
  float bb[16] = {b0.x, b0.y, b0.z, b0.w, b1.x, b1.y, b1.z, b1.w,
                  b2.x, b2.y, b2.z, b2.w, b3.x, b3.y, b3.z, b3.w};
  unsigned u[8];
  #pragma unroll
  for (int k = 0; k < 8; ++k) {
    float v0 = fmaxf(di * a[2 * k]     + bb[2 * k],     0.f);
    float v1 = fmaxf(di * a[2 * k + 1] + bb[2 * k + 1], 0.f);
    u[k] = (unsigned)bf16_rtn(v0) | ((unsigned)bf16_rtn(v1) << 16);
  }
  uint4* hp = (uint4*)(h + (size_t)i * 128 + 16 * l8);
  hp[0] = make_uint4(u[0], u[1], u[2], u[3]);
  hp[1] = make_uint4(u[4], u[5], u[6], u[7]);
}

// ---------------- fused final aggregate + mean-pool (block = 32 nodes) ----------------
__global__ __launch_bounds__(256)
void k_agg_pool(const unsigned char* __restrict__ tin,
                const int* __restrict__ rowptr,
                const int2* __restrict__ epack,
                const float* __restrict__ dpk, const float* __restrict__ bvec,
                const int* __restrict__ batch,
                float* __restrict__ pooled, int N) {
  __shared__ float sh[32][128];
  __shared__ int sg[32];
  int lane = threadIdx.x & 63;
  int g8 = lane >> 3, l8 = lane & 7;
  int nloc = (threadIdx.x >> 6) * 8 + g8;   // 0..31
  int i = blockIdx.x * 32 + nloc;
  if (threadIdx.x < 32) sg[threadIdx.x] = -1;
  __syncthreads();
  if (i < N) {
    int r0 = rowptr[i], r1 = rowptr[i + 1];
    uint4 ps = *(const uint4*)(tin + (size_t)i * 128 + (l8 << 4));
    float dp = dpk[i];

    float a[16];
    #pragma unroll
    for (int k = 0; k < 16; ++k) a[k] = 0.f;
    gather8(tin, epack, r0, r1 - r0, l8, N, a);
    acc16(a, ps);

    float di = fabsf(dp);
    const float4* bp = (const float4*)(bvec + 16 * l8);
    float4 b0 = bp[0], b1 = bp[1], b2 = bp[2], b3 = bp[3];
    float bb[16] = {b0.x, b0.y, b0.z, b0.w, b1.x, b1.y, b1.z, b1.w,
                    b2.x, b2.y, b2.z, b2.w, b3.x, b3.y, b3.z, b3.w};
    #pragma unroll
    for (int k = 0; k < 16; ++k)
      sh[nloc][16 * l8 + k] = di * a[k] + bb[k];
    if (l8 == 0) sg[nloc] = batch[i];
  }
  __syncthreads();
  if (threadIdx.x < 128) {
    int c = threadIdx.x;
    float acc = 0.f;
    int cur = sg[0];
    #pragma unroll
    for (int w2 = 0; w2 < 32; ++w2) {
      int gw = sg[w2];
      if (gw < 0) break;
      if (gw != cur) {
        atomicAdd(&pooled[cur * 128 + c], acc);
        acc = 0.f;
        cur = gw;
      }
      acc += sh[w2][c];
    }
    atomicAdd(&pooled[cur * 128 + c], acc);
  }
}

// ---------------- standalone MFMA GEMM: t' = dinv * (h @ W), fp8 out ----------------
__global__ void k_gemm(const unsigned short* __restrict__ h,
                       const unsigned short* __restrict__ wphi,
                       const unsigned short* __restrict__ wplo,
                       const float* __restrict__ dpk,
                       unsigned char* __restrict__ tout, int N) {
  int wave = threadIdx.x >> 6;
  int lane = threadIdx.x & 63;
  int r0 = (blockIdx.x * 4 + wave) * 32;
  if (r0 >= N) return;
  int q = lane >> 4;
  int m = lane & 15;
  const bf16x8* bh_base = (const bf16x8*)wphi;
  const bf16x8* bl_base = (const bf16x8*)wplo;

  f32x4 acc[2][8];
  #pragma unroll
  for (int tt = 0; tt < 2; ++tt)
    #pragma unroll
    for (int ct = 0; ct < 8; ++ct)
      acc[tt][ct] = (f32x4){0.f, 0.f, 0.f, 0.f};

  for (int c = 0; c < 4; ++c) {
    bf16x8 a0 = *(const bf16x8*)(h + (size_t)(r0 + m) * 128 + c * 32 + q * 8);
    bf16x8 a1 = *(const bf16x8*)(h + (size_t)(r0 + 16 + m) * 128 + c * 32 + q * 8);
    #pragma unroll
    for (int ct = 0; ct < 8; ++ct) {
      bf16x8 bh = bh_base[(ct * 4 + c) * 64 + lane];
      bf16x8 bl = bl_base[(ct * 4 + c) * 64 + lane];
      acc[0][ct] = __builtin_amdgcn_mfma_f32_16x16x32_bf16(a0, bh, acc[0][ct], 0, 0, 0);
      acc[0][ct] = __builtin_amdgcn_mfma_f32_16x16x32_bf16(a0, bl, acc[0][ct], 0, 0, 0);
      acc[1][ct] = __builtin_amdgcn_mfma_f32_16x16x32_bf16(a1, bh, acc[1][ct], 0, 0, 0);
      acc[1][ct] = __builtin_amdgcn_mfma_f32_16x16x32_bf16(a1, bl, acc[1][ct], 0, 0, 0);
    }
  }

  #pragma unroll
  for (int tt = 0; tt < 2; ++tt)
    #pragma unroll
    for (int ct = 0; ct < 8; ++ct)
      #pragma unroll
      for (int r = 0; r < 4; ++r) {
        int row = r0 + tt * 16 + q * 4 + r;
        if (row < N) {
          float sc = fabsf(dpk[row]);
          tout[(size_t)row * 128 + ct * 16 + m] = f_to_fp8(sc * acc[tt][ct][r]);
        }
      }
}

// ---------------- fused layer0 (rank-2) + gemm1 -> t1' ----------------
__device__ inline void gemm_tile8(const unsigned short* hT,
                                  const unsigned short* __restrict__ wphi,
                                  const unsigned short* __restrict__ wplo,
                                  const float* __restrict__ dpk,
                                  unsigned char* __restrict__ tout, int i0, int N) {
  int ct = threadIdx.x >> 6;
  int lane = threadIdx.x & 63;
  int q = lane >> 4;
  int m = lane & 15;
  const bf16x8* bh_base = (const bf16x8*)wphi;
  const bf16x8* bl_base = (const bf16x8*)wplo;

  f32x4 acc0 = (f32x4){0.f, 0.f, 0.f, 0.f};
  f32x4 acc1 = (f32x4){0.f, 0.f, 0.f, 0.f};

  #pragma unroll
  for (int c = 0; c < 4; ++c) {
    bf16x8 a0 = *(const bf16x8*)(hT + (m) * 136 + c * 32 + q * 8);
    bf16x8 a1 = *(const bf16x8*)(hT + (16 + m) * 136 + c * 32 + q * 8);
    bf16x8 bh = bh_base[(ct * 4 + c) * 64 + lane];
    bf16x8 bl = bl_base[(ct * 4 + c) * 64 + lane];
    acc0 = __builtin_amdgcn_mfma_f32_16x16x32_bf16(a0, bh, acc0, 0, 0, 0);
    acc0 = __builtin_amdgcn_mfma_f32_16x16x32_bf16(a0, bl, acc0, 0, 0, 0);
    acc1 = __builtin_amdgcn_mfma_f32_16x16x32_bf16(a1, bh, acc1, 0, 0, 0);
    acc1 = __builtin_amdgcn_mfma_f32_16x16x32_bf16(a1, bl, acc1, 0, 0, 0);
  }

  #pragma unroll
  for (int r = 0; r < 4; ++r) {
    int row0 = i0 + q * 4 + r;
    int row1 = row0 + 16;
    if (row0 < N) {
      float sc = fabsf(dpk[row0]);
      tout[(size_t)row0 * 128 + ct * 16 + m] = f_to_fp8(sc * acc0[r]);
    }
    if (row1 < N) {
      float sc = fabsf(dpk[row1]);
      tout[(size_t)row1 * 128 + ct * 16 + m] = f_to_fp8(sc * acc1[r]);
    }
  }
}

__global__ __launch_bounds__(512)
void k_l1_gemm(const int* __restrict__ rowptr,
               const int2* __restrict__ epack,
               const float* __restrict__ dpk, const float* __restrict__ T,
               const float* __restrict__ b0,
               const unsigned short* __restrict__ wphi,
               const unsigned short* __restrict__ wplo,
               unsigned char* __restrict__ tout, int N) {
  __shared__ unsigned short hT[32 * 136];
  int wave = threadIdx.x >> 6;
  int lane = threadIdx.x & 63;
  int i0 = blockIdx.x * 32;

  for (int j = wave * 4; j < wave * 4 + 4; ++j) {
    int i = i0 + j;
    if (i >= N) break;
    int r0 = rowptr[i], r1 = rowptr[i + 1];
    float sabs = 0.f, sneg = 0.f;
    for (int e = r0 + lane; e < r1; e += 64) {
      float wv = __int_as_float(epack[e].y);   // dpk[src]
      float aw = fabsf(wv);
      sabs += aw;
      if (wv < 0.f) sneg += aw;
    }
    for (int mm = 32; mm >= 1; mm >>= 1) {
      sabs += __shfl_xor(sabs, mm, 64);
      sneg += __shfl_xor(sneg, mm, 64);
    }
    float dp = dpk[i];
    float di = fabsf(dp);
    float sn = di * di;
    float c1 = di * sneg;
    float c0 = di * (sabs - sneg);
    if (dp < 0.f) c1 += sn; else c0 += sn;
    float v0 = fmaxf(c0 * T[2 * lane]     + c1 * T[128 + 2 * lane]     + b0[2 * lane],     0.f);
    float v1 = fmaxf(c0 * T[2 * lane + 1] + c1 * T[128 + 2 * lane + 1] + b0[2 * lane + 1], 0.f);
    *(unsigned*)&hT[j * 136 + 2 * lane] = (unsigned)bf16_rtn(v0) | ((unsigned)bf16_rtn(v1) << 16);
  }
  __syncthreads();
  gemm_tile8(hT, wphi, wplo, dpk, tout, i0, N);
}

// ---------------- output head ----------------
__global__ void k_out(const float* __restrict__ pooled, const int* __restrict__ gstart,
                      const int* __restrict__ gend, const float* __restrict__ W_out,
                      const float* __restrict__ b_out, float* __restrict__ out, int G) {
  __shared__ float sp[128];
  int g = blockIdx.x;
  int j = threadIdx.x;
  float cnt = (float)(gend[g] - gstart[g]);
  sp[j] = pooled[g * 128 + j] / fmaxf(cnt, 1.f);
  __syncthreads();
  if (j < 2) {
    float o = b_out[j];
    for (int k = 0; k < 128; ++k)
      o += sp[k] * W_out[k * 2 + j];
    out[g * 2 + j] = o;
  }
}

extern "C" void kernel_launch(void* const* d_in, const int* in_sizes, int n_in,
                              void* d_out, int out_size, void* d_ws, size_t ws_size,
                              hipStream_t stream) {
  const int*   x     = (const int*)d_in[0];
  const int*   ei    = (const int*)d_in[1];
  const int*   batch = (const int*)d_in[2];
  const float* embed = (const float*)d_in[3];
  const float* Ws    = (const float*)d_in[4];
  const float* bs    = (const float*)d_in[5];
  const float* W_out = (const float*)d_in[6];
  const float* b_out = (const float*)d_in[7];
  float* out = (float*)d_out;

  int N = in_sizes[2];
  int E = in_sizes[1] / 2;
  int G = out_size / 2;

  const int* src = ei;
  const int* dst = ei + E;

  char* w = (char*)d_ws;
  auto alloc = [&](size_t bytes) {
    char* p = w;
    w += (bytes + 255) & ~(size_t)255;
    return p;
  };
  int*   deg    = (int*)  alloc((size_t)N * 4);
  float* dpk    = (float*)alloc((size_t)N * 4);
  int*   rowptr = (int*)  alloc((size_t)(N + 1) * 4);
  int*   posr   = (int*)  alloc((size_t)E * 4);
  int*   bsum   = (int*)  alloc(512 * 4);
  // gstart/gend/pooled contiguous -> zeroed together in k_init
  int*   gstart = (int*)  alloc((size_t)G * 4);
  int*   gend   = (int*)  alloc((size_t)G * 4);
  float* pooled = (float*)alloc((size_t)G * 128 * 4);
  float* T      = (float*)alloc(256 * 4);
  unsigned short* wphi = (unsigned short*)alloc((size_t)3 * 16384 * 2);
  unsigned short* wplo = (unsigned short*)alloc((size_t)3 * 16384 * 2);
  int2*  epack  = (int2*) alloc((size_t)E * 8);
  unsigned short* h = (unsigned short*)alloc((size_t)N * 128 * 2);
  unsigned char* t_a = (unsigned char*)alloc((size_t)(N + 1) * 128);  // +1: zero row
  unsigned char* t_b = (unsigned char*)alloc((size_t)(N + 1) * 128);  // +1: zero row

  int nbN = (N + 255) / 256;
  int nbE = (E + 255) / 256;
  int ntile = (N + 31) / 32;
  int nagg = (N + 31) / 32;         // 32 nodes/block (8 per wave x 4 waves)
  int ngemm = (N + 127) / 128;      // 4 waves x 32 rows
  int M = G * 130;                  // gstart + gend + pooled (4B elems, contiguous)

  k_init<<<nbN, 256, 0, stream>>>(deg, gstart, N, M, Ws, embed, wphi, wplo, T, t_a, t_b);
  k_hist<<<nbE, 256, 0, stream>>>(dst, deg, posr, E);
  k_scan1<<<nbN, 256, 0, stream>>>(deg, rowptr, bsum, dpk, x, batch, gstart, gend, N);
  k_scanB<<<nbN, 256, 0, stream>>>(rowptr, bsum, N, E);
  k_scatter<<<nbE, 256, 0, stream>>>(src, dst, posr, rowptr, dpk, epack, E);

  // layer0 (rank-2) + gemm1 -> t_a (= dinv * h1@W1)
  k_l1_gemm<<<ntile, 512, 0, stream>>>(rowptr, epack, dpk, T, bs,
                                       wphi, wplo, t_a, N);
  // layer1: h = relu(dinv*(sum t_a' + self) + b1); t_b = dinv * h@W2
  k_agg<<<nagg, 256, 0, stream>>>(t_a, rowptr, epack, dpk, bs + 128, h, N);
  k_gemm<<<ngemm, 256, 0, stream>>>(h, wphi + 16384, wplo + 16384, dpk, t_b, N);
  // layer2
  k_agg<<<nagg, 256, 0, stream>>>(t_b, rowptr, epack, dpk, bs + 256, h, N);
  k_gemm<<<ngemm, 256, 0, stream>>>(h, wphi + 32768, wplo + 32768, dpk, t_a, N);
  // layer3 (no relu) fused with mean-pool
  k_agg_pool<<<nagg, 256, 0, stream>>>(t_a, rowptr, epack, dpk, bs + 384,
                                       batch, pooled, N);
  k_out<<<G, 128, 0, stream>>>(pooled, gstart, gend, W_out, b_out, out, G);
}